// Round 1
// baseline (2447.752 us; speedup 1.0000x reference)
//
#include <hip/hip_runtime.h>
#include <math.h>

#define B_   2
#define L_   1024
#define H_   8
#define DH_  128
#define NH_  2
#define HID_ 2048
#define T_   (L_ * NH_)    // 2048
#define KEY_ (H_ * DH_)    // 1024

// ---------------- f32 GEMM (NT): C[M,N] = X[M,K] * W[N,K]^T ----------------
__global__ __launch_bounds__(256) void gemm_nt_f32(
    const float* __restrict__ X, const float* __restrict__ W,
    float* __restrict__ C, int M, int N, int K) {
  __shared__ float As[16][65];
  __shared__ float Bs[16][65];
  const int bm = blockIdx.y * 64, bn = blockIdx.x * 64;
  const int tid = threadIdx.x;
  const int tx = tid & 15, ty = tid >> 4;
  const int lrow = tid >> 2, lks = (tid & 3) * 4;
  float acc[4][4] = {};
  for (int k0 = 0; k0 < K; k0 += 16) {
    const float4 a = *(const float4*)(X + (size_t)(bm + lrow) * K + k0 + lks);
    const float4 b = *(const float4*)(W + (size_t)(bn + lrow) * K + k0 + lks);
    As[lks + 0][lrow] = a.x; As[lks + 1][lrow] = a.y;
    As[lks + 2][lrow] = a.z; As[lks + 3][lrow] = a.w;
    Bs[lks + 0][lrow] = b.x; Bs[lks + 1][lrow] = b.y;
    Bs[lks + 2][lrow] = b.z; Bs[lks + 3][lrow] = b.w;
    __syncthreads();
#pragma unroll
    for (int kk = 0; kk < 16; ++kk) {
      float av[4], bv[4];
#pragma unroll
      for (int i = 0; i < 4; ++i) av[i] = As[kk][ty * 4 + i];
#pragma unroll
      for (int j = 0; j < 4; ++j) bv[j] = Bs[kk][tx * 4 + j];
#pragma unroll
      for (int i = 0; i < 4; ++i)
#pragma unroll
        for (int j = 0; j < 4; ++j)
          acc[i][j] = fmaf(av[i], bv[j], acc[i][j]);
    }
    __syncthreads();
  }
#pragma unroll
  for (int i = 0; i < 4; ++i)
#pragma unroll
    for (int j = 0; j < 4; ++j)
      C[(size_t)(bm + ty * 4 + i) * N + bn + tx * 4 + j] = acc[i][j];
}

// ---------------- small-N GEMM: one wave per output element ----------------
__global__ __launch_bounds__(256) void gemm_small(
    const float* __restrict__ X, const float* __restrict__ W,
    float* __restrict__ C, int M, int N, int K) {
  const int wid = blockIdx.x * 4 + (threadIdx.x >> 6);
  const int lane = threadIdx.x & 63;
  const int m = wid / N, n = wid - m * N;
  const float* xr = X + (size_t)m * K;
  const float* wr = W + (size_t)n * K;
  float s = 0.f;
  for (int k = lane * 4; k < K; k += 256) {
    const float4 a = *(const float4*)(xr + k);
    const float4 b = *(const float4*)(wr + k);
    s = fmaf(a.x, b.x, s); s = fmaf(a.y, b.y, s);
    s = fmaf(a.z, b.z, s); s = fmaf(a.w, b.w, s);
  }
#pragma unroll
  for (int mm = 32; mm; mm >>= 1) s += __shfl_xor(s, mm);
  if (lane == 0) C[(size_t)m * N + n] = s;
}

// ------------- causal depthwise conv(K=4) + SiLU (+ optional L2 norm) -------------
template <int NORM>
__global__ __launch_bounds__(128) void conv_silu_norm(
    const float* __restrict__ in, const float* __restrict__ cw,
    float* __restrict__ out, int C, float scale) {
  const int bl = blockIdx.x;            // b*L + l
  const int l = bl & (L_ - 1);
  const int c = blockIdx.y * 128 + threadIdx.x;
  const size_t base = (size_t)bl * C + c;
  const float w0 = cw[c * 4 + 0], w1 = cw[c * 4 + 1];
  const float w2 = cw[c * 4 + 2], w3 = cw[c * 4 + 3];
  float acc = w3 * in[base];
  if (l >= 1) acc = fmaf(w2, in[base - (size_t)C], acc);
  if (l >= 2) acc = fmaf(w1, in[base - 2 * (size_t)C], acc);
  if (l >= 3) acc = fmaf(w0, in[base - 3 * (size_t)C], acc);
  float y = acc / (1.f + expf(-acc));   // silu
  if (NORM) {
    float ss = y * y;
#pragma unroll
    for (int mm = 32; mm; mm >>= 1) ss += __shfl_xor(ss, mm);
    __shared__ float p[2];
    if ((threadIdx.x & 63) == 0) p[threadIdx.x >> 6] = ss;
    __syncthreads();
    const float tot = p[0] + p[1];
    y *= scale / fmaxf(sqrtf(tot), 1e-12f);
  }
  out[base] = y;
}

// ---------------- sequential gated delta-product scan ----------------
// One wave (64 lanes) owns an 8-column slab of one (b,h) 128x128 state.
// lane = kg*8 + vl: column v = vb*8+vl, rows kg*16 .. kg*16+15 (16 cells).
struct Tok {
  float4 k0[4], k1[4], q[4];
  float v0, v1, a, b0, b1;
};

__device__ __forceinline__ void load_tok(Tok& t, int l,
    const float* __restrict__ kp, const float* __restrict__ vp,
    const float* __restrict__ qp, const float* __restrict__ aap,
    const float* __restrict__ bap) {
  const float* kpt = kp + (size_t)(2 * l) * 1024;
#pragma unroll
  for (int c = 0; c < 4; ++c) t.k0[c] = *(const float4*)(kpt + c * 4);
#pragma unroll
  for (int c = 0; c < 4; ++c) t.k1[c] = *(const float4*)(kpt + 1024 + c * 4);
  t.v0 = vp[(size_t)(2 * l) * 1024];
  t.v1 = vp[(size_t)(2 * l) * 1024 + 1024];
  const float* qpt = qp + (size_t)l * 1024;
#pragma unroll
  for (int c = 0; c < 4; ++c) t.q[c] = *(const float4*)(qpt + c * 4);
  t.a = aap[l * 8];
  t.b0 = bap[l * 16];
  t.b1 = bap[l * 16 + 8];
}

__device__ __forceinline__ void proc_tok(const Tok& t, int l, float aln, float dtb,
                                         float st[16], int kg, float* __restrict__ op) {
  // ---- sub-step 0: gated decay, delta update (no query) ----
  const float xsp = t.a + dtb;
  const float sp = (xsp > 20.f) ? xsp : log1pf(expf(xsp));
  const float decay = expf(aln * sp);
  const float beta0 = 2.f / (1.f + expf(-t.b0));
  float corr = 0.f;
#pragma unroll
  for (int c = 0; c < 4; ++c) {
    const float4 kk = t.k0[c];
    st[c * 4 + 0] *= decay; corr = fmaf(kk.x, st[c * 4 + 0], corr);
    st[c * 4 + 1] *= decay; corr = fmaf(kk.y, st[c * 4 + 1], corr);
    st[c * 4 + 2] *= decay; corr = fmaf(kk.z, st[c * 4 + 2], corr);
    st[c * 4 + 3] *= decay; corr = fmaf(kk.w, st[c * 4 + 3], corr);
  }
  corr += __shfl_xor(corr, 8);
  corr += __shfl_xor(corr, 16);
  corr += __shfl_xor(corr, 32);
  float vnew = (t.v0 - corr) * beta0;
#pragma unroll
  for (int c = 0; c < 4; ++c) {
    const float4 kk = t.k0[c];
    st[c * 4 + 0] = fmaf(kk.x, vnew, st[c * 4 + 0]);
    st[c * 4 + 1] = fmaf(kk.y, vnew, st[c * 4 + 1]);
    st[c * 4 + 2] = fmaf(kk.z, vnew, st[c * 4 + 2]);
    st[c * 4 + 3] = fmaf(kk.w, vnew, st[c * 4 + 3]);
  }
  // ---- sub-step 1: no decay, delta update + query output ----
  const float beta1 = 2.f / (1.f + expf(-t.b1));
  corr = 0.f;
#pragma unroll
  for (int c = 0; c < 4; ++c) {
    const float4 kk = t.k1[c];
    corr = fmaf(kk.x, st[c * 4 + 0], corr);
    corr = fmaf(kk.y, st[c * 4 + 1], corr);
    corr = fmaf(kk.z, st[c * 4 + 2], corr);
    corr = fmaf(kk.w, st[c * 4 + 3], corr);
  }
  corr += __shfl_xor(corr, 8);
  corr += __shfl_xor(corr, 16);
  corr += __shfl_xor(corr, 32);
  vnew = (t.v1 - corr) * beta1;
  float osum = 0.f;
#pragma unroll
  for (int c = 0; c < 4; ++c) {
    const float4 kk = t.k1[c];
    const float4 qq = t.q[c];
    st[c * 4 + 0] = fmaf(kk.x, vnew, st[c * 4 + 0]); osum = fmaf(qq.x, st[c * 4 + 0], osum);
    st[c * 4 + 1] = fmaf(kk.y, vnew, st[c * 4 + 1]); osum = fmaf(qq.y, st[c * 4 + 1], osum);
    st[c * 4 + 2] = fmaf(kk.z, vnew, st[c * 4 + 2]); osum = fmaf(qq.z, st[c * 4 + 2], osum);
    st[c * 4 + 3] = fmaf(kk.w, vnew, st[c * 4 + 3]); osum = fmaf(qq.w, st[c * 4 + 3], osum);
  }
  osum += __shfl_xor(osum, 8);
  osum += __shfl_xor(osum, 16);
  osum += __shfl_xor(osum, 32);
  if (kg == 0) op[(size_t)l * 1024] = osum;
}

__global__ __launch_bounds__(64) void scan_kernel(
    const float* __restrict__ qn, const float* __restrict__ kn,
    const float* __restrict__ vc, const float* __restrict__ ba,
    const float* __restrict__ aa, const float* __restrict__ A_log,
    const float* __restrict__ dt_bias, float* __restrict__ o,
    float* __restrict__ fstate) {
  const int bid = blockIdx.x;       // b*128 + h*16 + vb
  const int vb = bid & 15;
  const int h = (bid >> 4) & 7;
  const int b = bid >> 7;
  const int lane = threadIdx.x;
  const int vl = lane & 7, kg = lane >> 3;
  const int v = vb * 8 + vl;
  const float aln = -expf(A_log[h]);
  const float dtb = dt_bias[h];
  const float* kp = kn + (size_t)b * T_ * 1024 + h * 128 + kg * 16;
  const float* vp = vc + (size_t)b * T_ * 1024 + h * 128 + v;
  const float* qp = qn + (size_t)b * L_ * 1024 + h * 128 + kg * 16;
  const float* aap = aa + (size_t)b * L_ * 8 + h;
  const float* bap = ba + (size_t)b * L_ * 16 + h;
  float* op = o + (size_t)b * L_ * 1024 + h * 128 + v;

  float st[16];
#pragma unroll
  for (int j = 0; j < 16; ++j) st[j] = 0.f;

  Tok A, Bt;
  load_tok(A, 0, kp, vp, qp, aap, bap);
  for (int l = 0; l < L_; l += 2) {
    load_tok(Bt, l + 1, kp, vp, qp, aap, bap);
    proc_tok(A, l, aln, dtb, st, kg, op);
    if (l + 2 < L_) load_tok(A, l + 2, kp, vp, qp, aap, bap);
    proc_tok(Bt, l + 1, aln, dtb, st, kg, op);
  }
  float* fp = fstate + (size_t)(b * H_ + h) * (128 * 128) + (size_t)(kg * 16) * 128 + v;
#pragma unroll
  for (int j = 0; j < 16; ++j) fp[j * 128] = st[j];
}

// ---------------- gated RMSNorm: on = rms(o)*w*silu(gg) ----------------
__global__ __launch_bounds__(128) void rmsnorm_gate(
    const float* __restrict__ o, const float* __restrict__ gg,
    const float* __restrict__ w, float* __restrict__ on) {
  const int blk = blockIdx.x;       // (b*L+l)*H + h
  const int d = threadIdx.x;
  const size_t base = (size_t)blk * 128 + d;
  const float x = o[base];
  float ss = x * x;
#pragma unroll
  for (int mm = 32; mm; mm >>= 1) ss += __shfl_xor(ss, mm);
  __shared__ float p[2];
  if ((d & 63) == 0) p[d >> 6] = ss;
  __syncthreads();
  const float tot = p[0] + p[1];
  const float r = rsqrtf(tot * (1.f / 128.f) + 1e-5f);
  const float gv = gg[base];
  on[base] = x * r * w[d] * (gv / (1.f + expf(-gv)));
}

extern "C" void kernel_launch(void* const* d_in, const int* in_sizes, int n_in,
                              void* d_out, int out_size, void* d_ws, size_t ws_size,
                              hipStream_t stream) {
  const float* x       = (const float*)d_in[0];
  const float* Wq      = (const float*)d_in[1];
  const float* Wk      = (const float*)d_in[2];
  const float* Wv      = (const float*)d_in[3];
  const float* Wb      = (const float*)d_in[4];
  const float* Wa      = (const float*)d_in[5];
  const float* Wg      = (const float*)d_in[6];
  const float* Wo      = (const float*)d_in[7];
  const float* A_log   = (const float*)d_in[8];
  const float* dt_bias = (const float*)d_in[9];
  const float* conv_q  = (const float*)d_in[10];
  const float* conv_k  = (const float*)d_in[11];
  const float* conv_v  = (const float*)d_in[12];
  const float* o_norm_w= (const float*)d_in[13];

  float* ws = (float*)d_ws;
  float* pa = ws;                 // 4,194,304 scratch (proj out, later on)
  float* kn = pa + 4194304;       // 4,194,304
  float* vc = kn + 4194304;       // 4,194,304
  float* qn = vc + 4194304;       // 2,097,152
  float* gg = qn + 2097152;       // 2,097,152
  float* ob = gg + 2097152;       // 2,097,152
  float* ba = ob + 2097152;       // 32,768
  float* aa = ba + 32768;         // 16,384  -> total ~75.7 MB

  float* out = (float*)d_out;
  float* fstate = out + (size_t)B_ * L_ * HID_;

  const int M = B_ * L_;          // 2048

  // k: proj -> conv+silu+l2norm
  gemm_nt_f32<<<dim3(2048 / 64, M / 64), 256, 0, stream>>>(x, Wk, pa, M, 2048, HID_);
  conv_silu_norm<1><<<dim3(M, 2048 / 128), 128, 0, stream>>>(pa, conv_k, kn, 2048, 1.0f);
  // v: proj -> conv+silu
  gemm_nt_f32<<<dim3(2048 / 64, M / 64), 256, 0, stream>>>(x, Wv, pa, M, 2048, HID_);
  conv_silu_norm<0><<<dim3(M, 2048 / 128), 128, 0, stream>>>(pa, conv_v, vc, 2048, 1.0f);
  // q: proj -> conv+silu+l2norm, scaled by 1/sqrt(DH)
  gemm_nt_f32<<<dim3(KEY_ / 64, M / 64), 256, 0, stream>>>(x, Wq, pa, M, KEY_, HID_);
  conv_silu_norm<1><<<dim3(M, KEY_ / 128), 128, 0, stream>>>(pa, conv_q, qn, KEY_,
                                                            0.08838834764831845f);
  // gate projection
  gemm_nt_f32<<<dim3(KEY_ / 64, M / 64), 256, 0, stream>>>(x, Wg, gg, M, KEY_, HID_);
  // beta / a projections
  gemm_small<<<dim3(M * 16 / 4), 256, 0, stream>>>(x, Wb, ba, M, 16, HID_);
  gemm_small<<<dim3(M * 8 / 4), 256, 0, stream>>>(x, Wa, aa, M, 8, HID_);
  // sequential scan (256 independent single-wave blocks)
  scan_kernel<<<dim3(B_ * H_ * 16), 64, 0, stream>>>(qn, kn, vc, ba, aa, A_log,
                                                     dt_bias, ob, fstate);
  // epilogue: gated RMSNorm then output projection
  rmsnorm_gate<<<dim3(M * H_), 128, 0, stream>>>(ob, gg, o_norm_w, pa);
  gemm_nt_f32<<<dim3(HID_ / 64, M / 64), 256, 0, stream>>>(pa, Wo, out, M, HID_, KEY_);
}

// Round 2
// 1397.931 us; speedup vs baseline: 1.7510x; 1.7510x over previous
//
#include <hip/hip_runtime.h>
#include <math.h>

#define B_   2
#define L_   1024
#define H_   8
#define DH_  128
#define NH_  2
#define HID_ 2048
#define T_   (L_ * NH_)    // 2048
#define KEY_ (H_ * DH_)    // 1024

typedef __attribute__((ext_vector_type(8))) short short8;
typedef __attribute__((ext_vector_type(4))) float f32x4;

__device__ __forceinline__ ushort f2bf(float f) {
  unsigned u = __float_as_uint(f);
  u += 0x7fffu + ((u >> 16) & 1u);
  return (ushort)(u >> 16);
}

// ---------------- f32 -> bf16 conversion (vectorized) ----------------
__global__ __launch_bounds__(256) void cvt_bf16(const float* __restrict__ in,
                                                ushort* __restrict__ out, int n4) {
  int i = blockIdx.x * 256 + threadIdx.x;
  if (i >= n4) return;
  float4 v = ((const float4*)in)[i];
  ushort4 o;
  o.x = f2bf(v.x); o.y = f2bf(v.y); o.z = f2bf(v.z); o.w = f2bf(v.w);
  ((ushort4*)out)[i] = o;
}

// ---------------- bf16 MFMA GEMM (NT): C[M,N] = A[M,K] * W[N,K]^T ----------------
__device__ __forceinline__ void gload16(const void* g, void* l) {
  __builtin_amdgcn_global_load_lds(
      (const __attribute__((address_space(1))) unsigned*)g,
      (__attribute__((address_space(3))) unsigned*)l, 16, 0, 0);
}

__global__ __launch_bounds__(256) void gemm_bf16(
    const ushort* __restrict__ A, const ushort* __restrict__ W,
    float* __restrict__ C, int M, int N, int K) {
  __shared__ __align__(16) ushort As[128 * 32];
  __shared__ __align__(16) ushort Bs[128 * 32];
  const int tid = threadIdx.x;
  const int lane = tid & 63, wid = tid >> 6;
  const int wr = wid >> 1, wc = wid & 1;
  const int bm = blockIdx.y * 128, bn = blockIdx.x * 128;
  // staging: thread t covers row t>>2, 16B chunk t&3 of the [128][32] bf16 tile
  const int srow = tid >> 2, sch = (tid & 3) * 8;
  const ushort* ga = A + (size_t)(bm + srow) * K + sch;
  const ushort* gb = W + (size_t)(bn + srow) * K + sch;
  ushort* la = As + tid * 8;       // linear LDS: row*32 + chunk*8 == tid*8
  ushort* lb = Bs + tid * 8;
  const int frow = lane & 15;      // A row / B col within 16x16 fragment
  const int fk = (lane >> 4) * 8;  // k-offset within BK=32
  f32x4 acc[4][4];
#pragma unroll
  for (int i = 0; i < 4; ++i)
#pragma unroll
    for (int j = 0; j < 4; ++j) acc[i][j] = (f32x4){0.f, 0.f, 0.f, 0.f};

  for (int k0 = 0; k0 < K; k0 += 32) {
    gload16(ga + k0, la);
    gload16(ga + k0 + (size_t)64 * K, la + 64 * 32);
    gload16(gb + k0, lb);
    gload16(gb + k0 + (size_t)64 * K, lb + 64 * 32);
    __syncthreads();               // drains vmcnt before barrier (compiler-emitted)
    short8 a[4], b[4];
#pragma unroll
    for (int m = 0; m < 4; ++m)
      a[m] = *(const short8*)(As + (wr * 64 + m * 16 + frow) * 32 + fk);
#pragma unroll
    for (int n = 0; n < 4; ++n)
      b[n] = *(const short8*)(Bs + (wc * 64 + n * 16 + frow) * 32 + fk);
#pragma unroll
    for (int m = 0; m < 4; ++m)
#pragma unroll
      for (int n = 0; n < 4; ++n)
        acc[m][n] = __builtin_amdgcn_mfma_f32_16x16x32_bf16(a[m], b[n], acc[m][n], 0, 0, 0);
    __syncthreads();               // readers done before next-tile staging
  }
  const int crow0 = (lane >> 4) * 4, ccol = lane & 15;  // C/D: col=lane&15, row=(lane>>4)*4+j
#pragma unroll
  for (int m = 0; m < 4; ++m)
#pragma unroll
    for (int n = 0; n < 4; ++n) {
      float* cp = C + (size_t)(bm + wr * 64 + m * 16 + crow0) * N + bn + wc * 64 + n * 16 + ccol;
#pragma unroll
      for (int j = 0; j < 4; ++j) cp[(size_t)j * N] = acc[m][n][j];
    }
}

// ---------------- small-N GEMM: one wave per output element ----------------
__global__ __launch_bounds__(256) void gemm_small(
    const float* __restrict__ X, const float* __restrict__ W,
    float* __restrict__ C, int M, int N, int K) {
  const int wid = blockIdx.x * 4 + (threadIdx.x >> 6);
  const int lane = threadIdx.x & 63;
  const int m = wid / N, n = wid - m * N;
  const float* xr = X + (size_t)m * K;
  const float* wr = W + (size_t)n * K;
  float s = 0.f;
  for (int k = lane * 4; k < K; k += 256) {
    const float4 a = *(const float4*)(xr + k);
    const float4 b = *(const float4*)(wr + k);
    s = fmaf(a.x, b.x, s); s = fmaf(a.y, b.y, s);
    s = fmaf(a.z, b.z, s); s = fmaf(a.w, b.w, s);
  }
#pragma unroll
  for (int mm = 32; mm; mm >>= 1) s += __shfl_xor(s, mm);
  if (lane == 0) C[(size_t)m * N + n] = s;
}

// ------------- causal depthwise conv(K=4) + SiLU (+ optional L2 norm) -------------
template <int NORM>
__global__ __launch_bounds__(128) void conv_silu_norm(
    const float* __restrict__ in, const float* __restrict__ cw,
    float* __restrict__ out, int C, float scale) {
  const int bl = blockIdx.x;            // b*L + l
  const int l = bl & (L_ - 1);
  const int c = blockIdx.y * 128 + threadIdx.x;
  const size_t base = (size_t)bl * C + c;
  const float w0 = cw[c * 4 + 0], w1 = cw[c * 4 + 1];
  const float w2 = cw[c * 4 + 2], w3 = cw[c * 4 + 3];
  float acc = w3 * in[base];
  if (l >= 1) acc = fmaf(w2, in[base - (size_t)C], acc);
  if (l >= 2) acc = fmaf(w1, in[base - 2 * (size_t)C], acc);
  if (l >= 3) acc = fmaf(w0, in[base - 3 * (size_t)C], acc);
  float y = acc / (1.f + expf(-acc));   // silu
  if (NORM) {
    float ss = y * y;
#pragma unroll
    for (int mm = 32; mm; mm >>= 1) ss += __shfl_xor(ss, mm);
    __shared__ float p[2];
    if ((threadIdx.x & 63) == 0) p[threadIdx.x >> 6] = ss;
    __syncthreads();
    const float tot = p[0] + p[1];
    y *= scale / fmaxf(sqrtf(tot), 1e-12f);
  }
  out[base] = y;
}

// ---------------- sequential gated delta-product scan ----------------
// One wave (64 lanes) owns an 8-column slab of one (b,h) 128x128 state.
// lane = kg*8 + vl: column v = vb*8+vl, rows kg*16 .. kg*16+15 (16 cells).
struct Tok {
  float4 k0[4], k1[4], q[4];
  float v0, v1, a, b0, b1;
};

__device__ __forceinline__ void load_tok(Tok& t, int l,
    const float* __restrict__ kp, const float* __restrict__ vp,
    const float* __restrict__ qp, const float* __restrict__ aap,
    const float* __restrict__ bap) {
  const float* kpt = kp + (size_t)(2 * l) * 1024;
#pragma unroll
  for (int c = 0; c < 4; ++c) t.k0[c] = *(const float4*)(kpt + c * 4);
#pragma unroll
  for (int c = 0; c < 4; ++c) t.k1[c] = *(const float4*)(kpt + 1024 + c * 4);
  t.v0 = vp[(size_t)(2 * l) * 1024];
  t.v1 = vp[(size_t)(2 * l) * 1024 + 1024];
  const float* qpt = qp + (size_t)l * 1024;
#pragma unroll
  for (int c = 0; c < 4; ++c) t.q[c] = *(const float4*)(qpt + c * 4);
  t.a = aap[l * 8];
  t.b0 = bap[l * 16];
  t.b1 = bap[l * 16 + 8];
}

__device__ __forceinline__ void proc_tok(const Tok& t, int l, float aln, float dtb,
                                         float st[16], int kg, float* __restrict__ op) {
  // ---- sub-step 0: gated decay, delta update (no query) ----
  const float xsp = t.a + dtb;
  const float sp = (xsp > 20.f) ? xsp : log1pf(expf(xsp));
  const float decay = expf(aln * sp);
  const float beta0 = 2.f / (1.f + expf(-t.b0));
  float corr = 0.f;
#pragma unroll
  for (int c = 0; c < 4; ++c) {
    const float4 kk = t.k0[c];
    st[c * 4 + 0] *= decay; corr = fmaf(kk.x, st[c * 4 + 0], corr);
    st[c * 4 + 1] *= decay; corr = fmaf(kk.y, st[c * 4 + 1], corr);
    st[c * 4 + 2] *= decay; corr = fmaf(kk.z, st[c * 4 + 2], corr);
    st[c * 4 + 3] *= decay; corr = fmaf(kk.w, st[c * 4 + 3], corr);
  }
  corr += __shfl_xor(corr, 8);
  corr += __shfl_xor(corr, 16);
  corr += __shfl_xor(corr, 32);
  float vnew = (t.v0 - corr) * beta0;
#pragma unroll
  for (int c = 0; c < 4; ++c) {
    const float4 kk = t.k0[c];
    st[c * 4 + 0] = fmaf(kk.x, vnew, st[c * 4 + 0]);
    st[c * 4 + 1] = fmaf(kk.y, vnew, st[c * 4 + 1]);
    st[c * 4 + 2] = fmaf(kk.z, vnew, st[c * 4 + 2]);
    st[c * 4 + 3] = fmaf(kk.w, vnew, st[c * 4 + 3]);
  }
  // ---- sub-step 1: no decay, delta update + query output ----
  const float beta1 = 2.f / (1.f + expf(-t.b1));
  corr = 0.f;
#pragma unroll
  for (int c = 0; c < 4; ++c) {
    const float4 kk = t.k1[c];
    corr = fmaf(kk.x, st[c * 4 + 0], corr);
    corr = fmaf(kk.y, st[c * 4 + 1], corr);
    corr = fmaf(kk.z, st[c * 4 + 2], corr);
    corr = fmaf(kk.w, st[c * 4 + 3], corr);
  }
  corr += __shfl_xor(corr, 8);
  corr += __shfl_xor(corr, 16);
  corr += __shfl_xor(corr, 32);
  vnew = (t.v1 - corr) * beta1;
  float osum = 0.f;
#pragma unroll
  for (int c = 0; c < 4; ++c) {
    const float4 kk = t.k1[c];
    const float4 qq = t.q[c];
    st[c * 4 + 0] = fmaf(kk.x, vnew, st[c * 4 + 0]); osum = fmaf(qq.x, st[c * 4 + 0], osum);
    st[c * 4 + 1] = fmaf(kk.y, vnew, st[c * 4 + 1]); osum = fmaf(qq.y, st[c * 4 + 1], osum);
    st[c * 4 + 2] = fmaf(kk.z, vnew, st[c * 4 + 2]); osum = fmaf(qq.z, st[c * 4 + 2], osum);
    st[c * 4 + 3] = fmaf(kk.w, vnew, st[c * 4 + 3]); osum = fmaf(qq.w, st[c * 4 + 3], osum);
  }
  osum += __shfl_xor(osum, 8);
  osum += __shfl_xor(osum, 16);
  osum += __shfl_xor(osum, 32);
  if (kg == 0) op[(size_t)l * 1024] = osum;
}

__global__ __launch_bounds__(64, 1) void scan_kernel(
    const float* __restrict__ qn, const float* __restrict__ kn,
    const float* __restrict__ vc, const float* __restrict__ ba,
    const float* __restrict__ aa, const float* __restrict__ A_log,
    const float* __restrict__ dt_bias, float* __restrict__ o,
    float* __restrict__ fstate) {
  // XCD-aware remap: all 16 vb-blocks of one (b,h) group land on ONE XCD
  // (XCD = blockIdx % 8 round-robin). bid = xcd + 8*(vb + 16*(g>>3)), g%8=xcd.
  const int bid = blockIdx.x;
  const int xcd = bid & 7;
  const int rest = bid >> 3;
  const int vb = rest & 15;
  const int g = ((rest >> 4) << 3) + xcd;   // (b,h) group id, 0..15
  const int h = g & 7;
  const int b = g >> 3;
  const int lane = threadIdx.x;
  const int vl = lane & 7, kg = lane >> 3;
  const int v = vb * 8 + vl;
  const float aln = -expf(A_log[h]);
  const float dtb = dt_bias[h];
  const float* kp = kn + (size_t)b * T_ * 1024 + h * 128 + kg * 16;
  const float* vp = vc + (size_t)b * T_ * 1024 + h * 128 + v;
  const float* qp = qn + (size_t)b * L_ * 1024 + h * 128 + kg * 16;
  const float* aap = aa + (size_t)b * L_ * 8 + h;
  const float* bap = ba + (size_t)b * L_ * 16 + h;
  float* op = o + (size_t)b * L_ * 1024 + h * 128 + v;

  float st[16];
#pragma unroll
  for (int j = 0; j < 16; ++j) st[j] = 0.f;

  // depth-4 prefetch ring: load for token l+4 issued 3 proc_toks before use
  Tok t0, t1, t2, t3;
  load_tok(t0, 0, kp, vp, qp, aap, bap);
  load_tok(t1, 1, kp, vp, qp, aap, bap);
  load_tok(t2, 2, kp, vp, qp, aap, bap);
  load_tok(t3, 3, kp, vp, qp, aap, bap);
  for (int l = 0; l < L_; l += 4) {
    proc_tok(t0, l, aln, dtb, st, kg, op);
    if (l + 4 < L_) load_tok(t0, l + 4, kp, vp, qp, aap, bap);
    proc_tok(t1, l + 1, aln, dtb, st, kg, op);
    if (l + 5 < L_) load_tok(t1, l + 5, kp, vp, qp, aap, bap);
    proc_tok(t2, l + 2, aln, dtb, st, kg, op);
    if (l + 6 < L_) load_tok(t2, l + 6, kp, vp, qp, aap, bap);
    proc_tok(t3, l + 3, aln, dtb, st, kg, op);
    if (l + 7 < L_) load_tok(t3, l + 7, kp, vp, qp, aap, bap);
  }
  float* fp = fstate + (size_t)(b * H_ + h) * (128 * 128) + (size_t)(kg * 16) * 128 + v;
#pragma unroll
  for (int j = 0; j < 16; ++j) fp[j * 128] = st[j];
}

// ---------------- gated RMSNorm: on = rms(o)*w*silu(gg), bf16 out ----------------
__global__ __launch_bounds__(128) void rmsnorm_gate(
    const float* __restrict__ o, const float* __restrict__ gg,
    const float* __restrict__ w, ushort* __restrict__ on) {
  const int blk = blockIdx.x;       // (b*L+l)*H + h
  const int d = threadIdx.x;
  const size_t base = (size_t)blk * 128 + d;
  const float x = o[base];
  float ss = x * x;
#pragma unroll
  for (int mm = 32; mm; mm >>= 1) ss += __shfl_xor(ss, mm);
  __shared__ float p[2];
  if ((d & 63) == 0) p[d >> 6] = ss;
  __syncthreads();
  const float tot = p[0] + p[1];
  const float r = rsqrtf(tot * (1.f / 128.f) + 1e-5f);
  const float gv = gg[base];
  on[base] = f2bf(x * r * w[d] * (gv / (1.f + expf(-gv))));
}

extern "C" void kernel_launch(void* const* d_in, const int* in_sizes, int n_in,
                              void* d_out, int out_size, void* d_ws, size_t ws_size,
                              hipStream_t stream) {
  const float* x       = (const float*)d_in[0];
  const float* Wq      = (const float*)d_in[1];
  const float* Wk      = (const float*)d_in[2];
  const float* Wv      = (const float*)d_in[3];
  const float* Wb      = (const float*)d_in[4];
  const float* Wa      = (const float*)d_in[5];
  const float* Wg      = (const float*)d_in[6];
  const float* Wo      = (const float*)d_in[7];
  const float* A_log   = (const float*)d_in[8];
  const float* dt_bias = (const float*)d_in[9];
  const float* conv_q  = (const float*)d_in[10];
  const float* conv_k  = (const float*)d_in[11];
  const float* conv_v  = (const float*)d_in[12];
  const float* o_norm_w= (const float*)d_in[13];

  float* ws = (float*)d_ws;
  float* pa = ws;                   // 4,194,304 f32 (proj scratch; later scan output)
  float* kn = pa + 4194304;         // 4,194,304 f32
  float* vc = kn + 4194304;         // 4,194,304 f32
  float* qn = vc + 4194304;         // 2,097,152 f32
  float* gg = qn + 2097152;         // 2,097,152 f32
  float* ba = gg + 2097152;         // 32,768 f32
  float* aa = ba + 32768;           // 16,384 f32
  ushort* xb  = (ushort*)(aa + 16384);        // 4,194,304 bf16
  ushort* wb  = xb + 4194304;                 // 4,194,304 bf16
  ushort* pab = wb + 4194304;                 // 2,097,152 bf16  (~88 MB total)

  float* out = (float*)d_out;
  float* fstate = out + (size_t)B_ * L_ * HID_;

  const int M = B_ * L_;            // 2048

  // x -> bf16 once
  cvt_bf16<<<4096, 256, 0, stream>>>(x, xb, 1048576);
  // k: proj -> conv+silu+l2norm
  cvt_bf16<<<4096, 256, 0, stream>>>(Wk, wb, 1048576);
  gemm_bf16<<<dim3(16, 16), 256, 0, stream>>>(xb, wb, pa, M, 2048, HID_);
  conv_silu_norm<1><<<dim3(M, 16), 128, 0, stream>>>(pa, conv_k, kn, 2048, 1.0f);
  // v: proj -> conv+silu
  cvt_bf16<<<4096, 256, 0, stream>>>(Wv, wb, 1048576);
  gemm_bf16<<<dim3(16, 16), 256, 0, stream>>>(xb, wb, pa, M, 2048, HID_);
  conv_silu_norm<0><<<dim3(M, 16), 128, 0, stream>>>(pa, conv_v, vc, 2048, 1.0f);
  // q: proj -> conv+silu+l2norm, scaled by 1/sqrt(DH)
  cvt_bf16<<<2048, 256, 0, stream>>>(Wq, wb, 524288);
  gemm_bf16<<<dim3(8, 16), 256, 0, stream>>>(xb, wb, pa, M, KEY_, HID_);
  conv_silu_norm<1><<<dim3(M, 8), 128, 0, stream>>>(pa, conv_q, qn, KEY_,
                                                    0.08838834764831845f);
  // gate projection
  cvt_bf16<<<2048, 256, 0, stream>>>(Wg, wb, 524288);
  gemm_bf16<<<dim3(8, 16), 256, 0, stream>>>(xb, wb, gg, M, KEY_, HID_);
  // beta / a projections (tiny, f32)
  gemm_small<<<dim3(M * 16 / 4), 256, 0, stream>>>(x, Wb, ba, M, 16, HID_);
  gemm_small<<<dim3(M * 8 / 4), 256, 0, stream>>>(x, Wa, aa, M, 8, HID_);
  // sequential scan (256 independent single-wave blocks, XCD-grouped)
  scan_kernel<<<dim3(B_ * H_ * 16), 64, 0, stream>>>(qn, kn, vc, ba, aa, A_log,
                                                     dt_bias, pa, fstate);
  // epilogue: gated RMSNorm (bf16 out) then output projection
  rmsnorm_gate<<<dim3(M * H_), 128, 0, stream>>>(pa, gg, o_norm_w, pab);
  cvt_bf16<<<2048, 256, 0, stream>>>(Wo, wb, 524288);
  gemm_bf16<<<dim3(16, 16), 256, 0, stream>>>(pab, wb, out, M, HID_, KEY_);
}

// Round 4
// 888.083 us; speedup vs baseline: 2.7562x; 1.5741x over previous
//
#include <hip/hip_runtime.h>
#include <math.h>

#define B_   2
#define L_   1024
#define H_   8
#define DH_  128
#define NH_  2
#define HID_ 2048
#define T_   (L_ * NH_)    // 2048
#define KEY_ (H_ * DH_)    // 1024

typedef __attribute__((ext_vector_type(8))) short short8;
typedef __attribute__((ext_vector_type(4))) float f32x4;
typedef __attribute__((ext_vector_type(2))) float f32x2;

__device__ __forceinline__ ushort f2bf(float f) {
  unsigned u = __float_as_uint(f);
  u += 0x7fffu + ((u >> 16) & 1u);
  return (ushort)(u >> 16);
}

// ---------------- f32 -> bf16 conversion (vectorized) ----------------
__global__ __launch_bounds__(256) void cvt_bf16(const float* __restrict__ in,
                                                ushort* __restrict__ out, int n4) {
  int i = blockIdx.x * 256 + threadIdx.x;
  if (i >= n4) return;
  float4 v = ((const float4*)in)[i];
  ushort4 o;
  o.x = f2bf(v.x); o.y = f2bf(v.y); o.z = f2bf(v.z); o.w = f2bf(v.w);
  ((ushort4*)out)[i] = o;
}

// ---------------- bf16 MFMA GEMM (NT): C[M,N] = A[M,K] * W[N,K]^T ----------------
__device__ __forceinline__ void gload16(const void* g, void* l) {
  __builtin_amdgcn_global_load_lds(
      (const __attribute__((address_space(1))) unsigned*)g,
      (__attribute__((address_space(3))) unsigned*)l, 16, 0, 0);
}

__global__ __launch_bounds__(256) void gemm_bf16(
    const ushort* __restrict__ A, const ushort* __restrict__ W,
    float* __restrict__ C, int M, int N, int K) {
  __shared__ __align__(16) ushort As[128 * 32];
  __shared__ __align__(16) ushort Bs[128 * 32];
  const int tid = threadIdx.x;
  const int lane = tid & 63, wid = tid >> 6;
  const int wr = wid >> 1, wc = wid & 1;
  const int bm = blockIdx.y * 128, bn = blockIdx.x * 128;
  const int srow = tid >> 2, sch = (tid & 3) * 8;
  const ushort* ga = A + (size_t)(bm + srow) * K + sch;
  const ushort* gb = W + (size_t)(bn + srow) * K + sch;
  ushort* la = As + tid * 8;
  ushort* lb = Bs + tid * 8;
  const int frow = lane & 15;
  const int fk = (lane >> 4) * 8;
  f32x4 acc[4][4];
#pragma unroll
  for (int i = 0; i < 4; ++i)
#pragma unroll
    for (int j = 0; j < 4; ++j) acc[i][j] = (f32x4){0.f, 0.f, 0.f, 0.f};

  for (int k0 = 0; k0 < K; k0 += 32) {
    gload16(ga + k0, la);
    gload16(ga + k0 + (size_t)64 * K, la + 64 * 32);
    gload16(gb + k0, lb);
    gload16(gb + k0 + (size_t)64 * K, lb + 64 * 32);
    __syncthreads();
    short8 a[4], b[4];
#pragma unroll
    for (int m = 0; m < 4; ++m)
      a[m] = *(const short8*)(As + (wr * 64 + m * 16 + frow) * 32 + fk);
#pragma unroll
    for (int n = 0; n < 4; ++n)
      b[n] = *(const short8*)(Bs + (wc * 64 + n * 16 + frow) * 32 + fk);
#pragma unroll
    for (int m = 0; m < 4; ++m)
#pragma unroll
      for (int n = 0; n < 4; ++n)
        acc[m][n] = __builtin_amdgcn_mfma_f32_16x16x32_bf16(a[m], b[n], acc[m][n], 0, 0, 0);
    __syncthreads();
  }
  const int crow0 = (lane >> 4) * 4, ccol = lane & 15;
#pragma unroll
  for (int m = 0; m < 4; ++m)
#pragma unroll
    for (int n = 0; n < 4; ++n) {
      float* cp = C + (size_t)(bm + wr * 64 + m * 16 + crow0) * N + bn + wc * 64 + n * 16 + ccol;
#pragma unroll
      for (int j = 0; j < 4; ++j) cp[(size_t)j * N] = acc[m][n][j];
    }
}

// ------- small-N GEMM with fused nonlinearity epilogue -------
// MODE 0: identity   MODE 1: 2*sigmoid(s)   MODE 2: exp(-exp(A_log[n])*softplus(s+dt_bias[n]))
template <int MODE>
__global__ __launch_bounds__(256) void gemm_small(
    const float* __restrict__ X, const float* __restrict__ W,
    float* __restrict__ C, int M, int N, int K,
    const float* __restrict__ A_log, const float* __restrict__ dt_bias) {
  const int wid = blockIdx.x * 4 + (threadIdx.x >> 6);
  const int lane = threadIdx.x & 63;
  const int m = wid / N, n = wid - m * N;
  const float* xr = X + (size_t)m * K;
  const float* wr = W + (size_t)n * K;
  float s = 0.f;
  for (int k = lane * 4; k < K; k += 256) {
    const float4 a = *(const float4*)(xr + k);
    const float4 b = *(const float4*)(wr + k);
    s = fmaf(a.x, b.x, s); s = fmaf(a.y, b.y, s);
    s = fmaf(a.z, b.z, s); s = fmaf(a.w, b.w, s);
  }
#pragma unroll
  for (int mm = 32; mm; mm >>= 1) s += __shfl_xor(s, mm);
  if (lane == 0) {
    float r;
    if (MODE == 1) {
      r = 2.f / (1.f + expf(-s));
    } else if (MODE == 2) {
      const float xs = s + dt_bias[n];
      const float sp = (xs > 20.f) ? xs : log1pf(expf(xs));
      r = expf(-expf(A_log[n]) * sp);
    } else {
      r = s;
    }
    C[(size_t)m * N + n] = r;
  }
}

// ------------- causal depthwise conv(K=4) + SiLU (+ optional L2 norm) -------------
template <int NORM>
__global__ __launch_bounds__(128) void conv_silu_norm(
    const float* __restrict__ in, const float* __restrict__ cw,
    float* __restrict__ out, int C, float scale) {
  const int bl = blockIdx.x;            // b*L + l
  const int l = bl & (L_ - 1);
  const int c = blockIdx.y * 128 + threadIdx.x;
  const size_t base = (size_t)bl * C + c;
  const float w0 = cw[c * 4 + 0], w1 = cw[c * 4 + 1];
  const float w2 = cw[c * 4 + 2], w3 = cw[c * 4 + 3];
  float acc = w3 * in[base];
  if (l >= 1) acc = fmaf(w2, in[base - (size_t)C], acc);
  if (l >= 2) acc = fmaf(w1, in[base - 2 * (size_t)C], acc);
  if (l >= 3) acc = fmaf(w0, in[base - 3 * (size_t)C], acc);
  float y = acc / (1.f + expf(-acc));   // silu
  if (NORM) {
    float ss = y * y;
#pragma unroll
    for (int mm = 32; mm; mm >>= 1) ss += __shfl_xor(ss, mm);
    __shared__ float p[2];
    if ((threadIdx.x & 63) == 0) p[threadIdx.x >> 6] = ss;
    __syncthreads();
    const float tot = p[0] + p[1];
    y *= scale / fmaxf(sqrtf(tot), 1e-12f);
  }
  out[base] = y;
}

// ---------------- sequential gated delta-product scan ----------------
// lane = vl*8 + kg  (kg = lane&7, vl = lane>>3): column v = vb*8+vl,
// k-rows kg*16 .. kg*16+15 (16 cells as 8 f32x2). k-reduction over the
// low 3 lane bits -> pure-VALU DPP (quad_perm xor1, xor2, row_half_mirror).

__device__ __forceinline__ float dpp_red8(float x) {
  int t;
  t = __builtin_amdgcn_mov_dpp(__float_as_int(x), 0xB1, 0xf, 0xf, true);   // quad_perm [1,0,3,2]
  x += __int_as_float(t);
  t = __builtin_amdgcn_mov_dpp(__float_as_int(x), 0x4E, 0xf, 0xf, true);   // quad_perm [2,3,0,1]
  x += __int_as_float(t);
  t = __builtin_amdgcn_mov_dpp(__float_as_int(x), 0x141, 0xf, 0xf, true);  // row_half_mirror
  x += __int_as_float(t);
  return x;
}

union V16 {
  float4 v4[4];
  f32x2  v2[8];
};

struct Tok {
  V16 k0, k1, q;
  float v0, v1, dk, b0, b1;   // dk = decay, b0/b1 = 2*sigmoid(beta)
};

__device__ __forceinline__ void load_tok(Tok& t, int l,
    const float* __restrict__ kp, const float* __restrict__ vp,
    const float* __restrict__ qp, const float* __restrict__ dkp,
    const float* __restrict__ bap) {
  const float* kpt = kp + (size_t)(2 * l) * 1024;
#pragma unroll
  for (int c = 0; c < 4; ++c) t.k0.v4[c] = *(const float4*)(kpt + c * 4);
#pragma unroll
  for (int c = 0; c < 4; ++c) t.k1.v4[c] = *(const float4*)(kpt + 1024 + c * 4);
  t.v0 = vp[(size_t)(2 * l) * 1024];
  t.v1 = vp[(size_t)(2 * l) * 1024 + 1024];
  const float* qpt = qp + (size_t)l * 1024;
#pragma unroll
  for (int c = 0; c < 4; ++c) t.q.v4[c] = *(const float4*)(qpt + c * 4);
  t.dk = dkp[l * 8];
  t.b0 = bap[l * 16];
  t.b1 = bap[l * 16 + 8];
}

__device__ __forceinline__ void proc_tok(const Tok& t, int l,
                                         f32x2 st[8], int kg, float* __restrict__ op) {
  // ---- sub-step 0: decay, delta update (no query) ----
  const f32x2 d2 = {t.dk, t.dk};
  f32x2 a0 = {0.f, 0.f}, a1 = a0, a2 = a0, a3 = a0;
#pragma unroll
  for (int p = 0; p < 8; p += 4) {
    st[p + 0] *= d2;
    st[p + 1] *= d2;
    st[p + 2] *= d2;
    st[p + 3] *= d2;
    a0 = __builtin_elementwise_fma(t.k0.v2[p + 0], st[p + 0], a0);
    a1 = __builtin_elementwise_fma(t.k0.v2[p + 1], st[p + 1], a1);
    a2 = __builtin_elementwise_fma(t.k0.v2[p + 2], st[p + 2], a2);
    a3 = __builtin_elementwise_fma(t.k0.v2[p + 3], st[p + 3], a3);
  }
  f32x2 sp2 = (a0 + a1) + (a2 + a3);
  float corr = dpp_red8(sp2.x + sp2.y);
  const float vn0 = (t.v0 - corr) * t.b0;
  const f32x2 w0 = {vn0, vn0};
#pragma unroll
  for (int p = 0; p < 8; ++p)
    st[p] = __builtin_elementwise_fma(t.k0.v2[p], w0, st[p]);

  // ---- sub-step 1: no decay, delta update + query output ----
  a0 = (f32x2){0.f, 0.f}; a1 = a0; a2 = a0; a3 = a0;
#pragma unroll
  for (int p = 0; p < 8; p += 4) {
    a0 = __builtin_elementwise_fma(t.k1.v2[p + 0], st[p + 0], a0);
    a1 = __builtin_elementwise_fma(t.k1.v2[p + 1], st[p + 1], a1);
    a2 = __builtin_elementwise_fma(t.k1.v2[p + 2], st[p + 2], a2);
    a3 = __builtin_elementwise_fma(t.k1.v2[p + 3], st[p + 3], a3);
  }
  sp2 = (a0 + a1) + (a2 + a3);
  corr = dpp_red8(sp2.x + sp2.y);
  const float vn1 = (t.v1 - corr) * t.b1;
  const f32x2 w1 = {vn1, vn1};
  a0 = (f32x2){0.f, 0.f}; a1 = a0; a2 = a0; a3 = a0;
#pragma unroll
  for (int p = 0; p < 8; p += 4) {
    st[p + 0] = __builtin_elementwise_fma(t.k1.v2[p + 0], w1, st[p + 0]);
    st[p + 1] = __builtin_elementwise_fma(t.k1.v2[p + 1], w1, st[p + 1]);
    st[p + 2] = __builtin_elementwise_fma(t.k1.v2[p + 2], w1, st[p + 2]);
    st[p + 3] = __builtin_elementwise_fma(t.k1.v2[p + 3], w1, st[p + 3]);
    a0 = __builtin_elementwise_fma(t.q.v2[p + 0], st[p + 0], a0);
    a1 = __builtin_elementwise_fma(t.q.v2[p + 1], st[p + 1], a1);
    a2 = __builtin_elementwise_fma(t.q.v2[p + 2], st[p + 2], a2);
    a3 = __builtin_elementwise_fma(t.q.v2[p + 3], st[p + 3], a3);
  }
  sp2 = (a0 + a1) + (a2 + a3);
  const float osum = dpp_red8(sp2.x + sp2.y);
  if (kg == 0) op[(size_t)l * 1024] = osum;
}

__global__ __launch_bounds__(64, 1) void scan_kernel(
    const float* __restrict__ qn, const float* __restrict__ kn,
    const float* __restrict__ vc, const float* __restrict__ ba,
    const float* __restrict__ dka, float* __restrict__ o,
    float* __restrict__ fstate) {
  // XCD-aware remap: all 16 vb-blocks of one (b,h) group land on ONE XCD.
  const int bid = blockIdx.x;
  const int xcd = bid & 7;
  const int rest = bid >> 3;
  const int vb = rest & 15;
  const int g = ((rest >> 4) << 3) + xcd;   // (b,h) group id, 0..15
  const int h = g & 7;
  const int b = g >> 3;
  const int lane = threadIdx.x;
  const int kg = lane & 7, vl = lane >> 3;
  const int v = vb * 8 + vl;
  const float* kp = kn + (size_t)b * T_ * 1024 + h * 128 + kg * 16;
  const float* vp = vc + (size_t)b * T_ * 1024 + h * 128 + v;
  const float* qp = qn + (size_t)b * L_ * 1024 + h * 128 + kg * 16;
  const float* dkp = dka + (size_t)b * L_ * 8 + h;
  const float* bap = ba + (size_t)b * L_ * 16 + h;
  float* op = o + (size_t)b * L_ * 1024 + h * 128 + v;

  f32x2 st[8];
#pragma unroll
  for (int j = 0; j < 8; ++j) st[j] = (f32x2){0.f, 0.f};

  Tok t0, t1, t2, t3;
  load_tok(t0, 0, kp, vp, qp, dkp, bap);
  load_tok(t1, 1, kp, vp, qp, dkp, bap);
  load_tok(t2, 2, kp, vp, qp, dkp, bap);
  load_tok(t3, 3, kp, vp, qp, dkp, bap);
  for (int l = 0; l < L_; l += 4) {
    proc_tok(t0, l, st, kg, op);
    if (l + 4 < L_) load_tok(t0, l + 4, kp, vp, qp, dkp, bap);
    proc_tok(t1, l + 1, st, kg, op);
    if (l + 5 < L_) load_tok(t1, l + 5, kp, vp, qp, dkp, bap);
    proc_tok(t2, l + 2, st, kg, op);
    if (l + 6 < L_) load_tok(t2, l + 6, kp, vp, qp, dkp, bap);
    proc_tok(t3, l + 3, st, kg, op);
    if (l + 7 < L_) load_tok(t3, l + 7, kp, vp, qp, dkp, bap);
  }
  float* fp = fstate + (size_t)(b * H_ + h) * (128 * 128) + (size_t)(kg * 16) * 128 + v;
#pragma unroll
  for (int p = 0; p < 8; ++p) {
    fp[(size_t)(2 * p) * 128] = st[p].x;
    fp[(size_t)(2 * p + 1) * 128] = st[p].y;
  }
}

// ---------------- gated RMSNorm: on = rms(o)*w*silu(gg), bf16 out ----------------
__global__ __launch_bounds__(128) void rmsnorm_gate(
    const float* __restrict__ o, const float* __restrict__ gg,
    const float* __restrict__ w, ushort* __restrict__ on) {
  const int blk = blockIdx.x;       // (b*L+l)*H + h
  const int d = threadIdx.x;
  const size_t base = (size_t)blk * 128 + d;
  const float x = o[base];
  float ss = x * x;
#pragma unroll
  for (int mm = 32; mm; mm >>= 1) ss += __shfl_xor(ss, mm);
  __shared__ float p[2];
  if ((d & 63) == 0) p[d >> 6] = ss;
  __syncthreads();
  const float tot = p[0] + p[1];
  const float r = rsqrtf(tot * (1.f / 128.f) + 1e-5f);
  const float gv = gg[base];
  on[base] = f2bf(x * r * w[d] * (gv / (1.f + expf(-gv))));
}

extern "C" void kernel_launch(void* const* d_in, const int* in_sizes, int n_in,
                              void* d_out, int out_size, void* d_ws, size_t ws_size,
                              hipStream_t stream) {
  const float* x       = (const float*)d_in[0];
  const float* Wq      = (const float*)d_in[1];
  const float* Wk      = (const float*)d_in[2];
  const float* Wv      = (const float*)d_in[3];
  const float* Wb      = (const float*)d_in[4];
  const float* Wa      = (const float*)d_in[5];
  const float* Wg      = (const float*)d_in[6];
  const float* Wo      = (const float*)d_in[7];
  const float* A_log   = (const float*)d_in[8];
  const float* dt_bias = (const float*)d_in[9];
  const float* conv_q  = (const float*)d_in[10];
  const float* conv_k  = (const float*)d_in[11];
  const float* conv_v  = (const float*)d_in[12];
  const float* o_norm_w= (const float*)d_in[13];

  float* ws = (float*)d_ws;
  float* pa = ws;                   // 4,194,304 f32 (proj scratch; later scan output)
  float* kn = pa + 4194304;         // 4,194,304 f32
  float* vc = kn + 4194304;         // 4,194,304 f32
  float* qn = vc + 4194304;         // 2,097,152 f32
  float* gg = qn + 2097152;         // 2,097,152 f32
  float* ba = gg + 2097152;         // 32,768 f32  (pre-transformed: 2*sigmoid)
  float* dka = ba + 32768;          // 16,384 f32  (pre-transformed: decay)
  ushort* xb  = (ushort*)(dka + 16384);       // 4,194,304 bf16
  ushort* wb  = xb + 4194304;                 // 4,194,304 bf16
  ushort* pab = wb + 4194304;                 // 2,097,152 bf16

  float* out = (float*)d_out;
  float* fstate = out + (size_t)B_ * L_ * HID_;

  const int M = B_ * L_;            // 2048

  // x -> bf16 once
  cvt_bf16<<<4096, 256, 0, stream>>>(x, xb, 1048576);
  // k: proj -> conv+silu+l2norm
  cvt_bf16<<<4096, 256, 0, stream>>>(Wk, wb, 1048576);
  gemm_bf16<<<dim3(16, 16), 256, 0, stream>>>(xb, wb, pa, M, 2048, HID_);
  conv_silu_norm<1><<<dim3(M, 16), 128, 0, stream>>>(pa, conv_k, kn, 2048, 1.0f);
  // v: proj -> conv+silu
  cvt_bf16<<<4096, 256, 0, stream>>>(Wv, wb, 1048576);
  gemm_bf16<<<dim3(16, 16), 256, 0, stream>>>(xb, wb, pa, M, 2048, HID_);
  conv_silu_norm<0><<<dim3(M, 16), 128, 0, stream>>>(pa, conv_v, vc, 2048, 1.0f);
  // q: proj -> conv+silu+l2norm, scaled by 1/sqrt(DH)
  cvt_bf16<<<2048, 256, 0, stream>>>(Wq, wb, 524288);
  gemm_bf16<<<dim3(8, 16), 256, 0, stream>>>(xb, wb, pa, M, KEY_, HID_);
  conv_silu_norm<1><<<dim3(M, 8), 128, 0, stream>>>(pa, conv_q, qn, KEY_,
                                                    0.08838834764831845f);
  // gate projection
  cvt_bf16<<<2048, 256, 0, stream>>>(Wg, wb, 524288);
  gemm_bf16<<<dim3(8, 16), 256, 0, stream>>>(xb, wb, gg, M, KEY_, HID_);
  // beta / decay projections with fused nonlinearity
  gemm_small<1><<<dim3(M * 16 / 4), 256, 0, stream>>>(x, Wb, ba, M, 16, HID_, nullptr, nullptr);
  gemm_small<2><<<dim3(M * 8 / 4), 256, 0, stream>>>(x, Wa, dka, M, 8, HID_, A_log, dt_bias);
  // sequential scan (256 independent single-wave blocks, XCD-grouped, DPP reductions)
  scan_kernel<<<dim3(B_ * H_ * 16), 64, 0, stream>>>(qn, kn, vc, ba, dka, pa, fstate);
  // epilogue: gated RMSNorm (bf16 out) then output projection
  rmsnorm_gate<<<dim3(M * H_), 128, 0, stream>>>(pa, gg, o_norm_w, pab);
  cvt_bf16<<<2048, 256, 0, stream>>>(Wo, wb, 524288);
  gemm_bf16<<<dim3(16, 16), 256, 0, stream>>>(pab, wb, out, M, HID_, KEY_);
}